// Round 1
// baseline (1887.588 us; speedup 1.0000x reference)
//
#include <hip/hip_runtime.h>
#include <hip/hip_bf16.h>
#include <math.h>

// Shapes (fixed by the reference)
#define Bdim 16
#define Ndim 1024
#define Ddim 256
#define Hdim 8
#define HDdim 32
#define INdim 256
#define HIDdim 1024
#define Tdim (Bdim * Ndim)   // 16384 rows

// ---------------------------------------------------------------------------
// LayerNorm: one block per row (D=256, 256 threads)
// ---------------------------------------------------------------------------
__global__ __launch_bounds__(256) void ln_kernel(const float* __restrict__ x,
                                                 const float* __restrict__ g,
                                                 const float* __restrict__ b,
                                                 float* __restrict__ out) {
    int row = blockIdx.x;
    int tid = threadIdx.x;
    float v = x[(size_t)row * Ddim + tid];
    float s = v, s2 = v * v;
    #pragma unroll
    for (int off = 32; off; off >>= 1) {
        s  += __shfl_xor(s,  off, 64);
        s2 += __shfl_xor(s2, off, 64);
    }
    __shared__ float ws[8];
    int w = tid >> 6;
    if ((tid & 63) == 0) { ws[w] = s; ws[w + 4] = s2; }
    __syncthreads();
    s  = ws[0] + ws[1] + ws[2] + ws[3];
    s2 = ws[4] + ws[5] + ws[6] + ws[7];
    float mu   = s * (1.0f / Ddim);
    float var  = s2 * (1.0f / Ddim) - mu * mu;
    float rstd = rsqrtf(var + 1e-5f);
    out[(size_t)row * Ddim + tid] = (v - mu) * rstd * g[tid] + b[tid];
}

// ---------------------------------------------------------------------------
// fp32 tiled GEMM: C[M,N] = A[M,K] @ W[N,K]^T (+ epilogue)
// BM=128, BN=64, BK=16, 256 threads, 8x4 per-thread microtile
// ---------------------------------------------------------------------------
#define EPI_NONE 0
#define EPI_PROJ 1   // + bias[n] + add1[off] + add2[off]   (o@Wproj^T + bproj + h + x)
#define EPI_GELU 2   // gelu(acc + bias[n])
#define EPI_RES  3   // + bias[n] + add1[off]               (final residual)

__device__ inline float gelu_exact(float v) {
    return 0.5f * v * (1.0f + erff(v * 0.70710678118654752f));
}

template <int EPI>
__global__ __launch_bounds__(256) void gemm_kernel(const float* __restrict__ A,
                                                   const float* __restrict__ W,
                                                   float* __restrict__ C,
                                                   int M, int N, int K,
                                                   const float* __restrict__ bias,
                                                   const float* __restrict__ add1,
                                                   const float* __restrict__ add2) {
    __shared__ float As[16][132];  // [k][m], padded
    __shared__ float Wsh[16][68];  // [k][n], padded
    int tid = threadIdx.x;
    int bn = blockIdx.x, bm = blockIdx.y;
    int m0 = bm * 128, n0 = bn * 64;
    int tx = tid & 15, ty = tid >> 4;   // tx -> n (4 cols), ty -> m (8 rows)

    float acc[8][4];
    #pragma unroll
    for (int i = 0; i < 8; ++i)
        #pragma unroll
        for (int j = 0; j < 4; ++j) acc[i][j] = 0.0f;

    for (int k0 = 0; k0 < K; k0 += 16) {
        // stage A tile: 128 rows x 16 k  (512 float4s, 2 per thread), transpose to [k][m]
        #pragma unroll
        for (int i = 0; i < 2; ++i) {
            int f4 = tid + i * 256;
            int r = f4 >> 2, c = f4 & 3;
            float4 v = *(const float4*)&A[(size_t)(m0 + r) * K + k0 + c * 4];
            As[c * 4 + 0][r] = v.x;
            As[c * 4 + 1][r] = v.y;
            As[c * 4 + 2][r] = v.z;
            As[c * 4 + 3][r] = v.w;
        }
        // stage W tile: 64 rows x 16 k (256 float4s, 1 per thread)
        {
            int r = tid >> 2, c = tid & 3;
            float4 v = *(const float4*)&W[(size_t)(n0 + r) * K + k0 + c * 4];
            Wsh[c * 4 + 0][r] = v.x;
            Wsh[c * 4 + 1][r] = v.y;
            Wsh[c * 4 + 2][r] = v.z;
            Wsh[c * 4 + 3][r] = v.w;
        }
        __syncthreads();
        #pragma unroll
        for (int kk = 0; kk < 16; ++kk) {
            float4 a0 = *(const float4*)&As[kk][ty * 8];
            float4 a1 = *(const float4*)&As[kk][ty * 8 + 4];
            float4 w0 = *(const float4*)&Wsh[kk][tx * 4];
            float av[8] = {a0.x, a0.y, a0.z, a0.w, a1.x, a1.y, a1.z, a1.w};
            float wv[4] = {w0.x, w0.y, w0.z, w0.w};
            #pragma unroll
            for (int i = 0; i < 8; ++i)
                #pragma unroll
                for (int j = 0; j < 4; ++j)
                    acc[i][j] = fmaf(av[i], wv[j], acc[i][j]);
        }
        __syncthreads();
    }

    // epilogue
    #pragma unroll
    for (int i = 0; i < 8; ++i) {
        int m = m0 + ty * 8 + i;
        size_t off = (size_t)m * N + n0 + tx * 4;
        float4 r = make_float4(acc[i][0], acc[i][1], acc[i][2], acc[i][3]);
        if (EPI != EPI_NONE) {
            float4 bi = *(const float4*)&bias[n0 + tx * 4];
            r.x += bi.x; r.y += bi.y; r.z += bi.z; r.w += bi.w;
        }
        if (EPI == EPI_GELU) {
            r.x = gelu_exact(r.x); r.y = gelu_exact(r.y);
            r.z = gelu_exact(r.z); r.w = gelu_exact(r.w);
        }
        if (EPI == EPI_PROJ) {
            float4 h4 = *(const float4*)&add1[off];
            float4 x4 = *(const float4*)&add2[off];
            r.x += h4.x + x4.x; r.y += h4.y + x4.y;
            r.z += h4.z + x4.z; r.w += h4.w + x4.w;
        }
        if (EPI == EPI_RES) {
            float4 a4 = *(const float4*)&add1[off];
            r.x += a4.x; r.y += a4.y; r.z += a4.z; r.w += a4.w;
        }
        *(float4*)&C[off] = r;
    }
}

// ---------------------------------------------------------------------------
// Attention, fp32. One block = one (b,h) x 8 query rows. Full score row in LDS.
// qkv layout: [T, 768] with q at col h*32, k at 256+h*32, v at 512+h*32.
// Writes o as [T, 256] at col h*32+d.
// ---------------------------------------------------------------------------
#define TQ 8
__global__ __launch_bounds__(256) void attn_kernel(const float* __restrict__ qkv,
                                                   float* __restrict__ o) {
    __shared__ float S[TQ][1028];      // padded: stride 1028 -> conflict-free f4 reads
    __shared__ float4 Qs[TQ][8];
    __shared__ float sums[TQ];
    __shared__ float Opart[32][32];

    int bh = blockIdx.y;
    int b = bh >> 3, h = bh & 7;
    int n0 = blockIdx.x * TQ;
    int tid = threadIdx.x;
    const float scale = 0.17677669529663689f;  // 32^-0.5

    size_t base = (size_t)b * Ndim * 768;
    const float* qbase = qkv + base + (size_t)n0 * 768 + h * 32;
    const float* kbase = qkv + base + 256 + h * 32;
    const float* vbase = qkv + base + 512 + h * 32;

    // load Q tile (scaled)
    if (tid < TQ * 32) {
        int r = tid >> 5, d = tid & 31;
        ((float*)Qs)[tid] = qbase[(size_t)r * 768 + d] * scale;
    }
    __syncthreads();

    // Phase A: scores. Each thread handles 2 k-rows per half (register-cached).
    for (int half = 0; half < 2; ++half) {
        int ja = half * 512 + tid;
        int jb = ja + 256;
        float4 ka[8], kb[8];
        const float* kra = kbase + (size_t)ja * 768;
        const float* krb = kbase + (size_t)jb * 768;
        #pragma unroll
        for (int c = 0; c < 8; ++c) {
            ka[c] = ((const float4*)kra)[c];
            kb[c] = ((const float4*)krb)[c];
        }
        #pragma unroll
        for (int qr = 0; qr < TQ; ++qr) {
            float s1 = 0.0f, s2 = 0.0f;
            #pragma unroll
            for (int c = 0; c < 8; ++c) {
                float4 q4 = Qs[qr][c];
                s1 = fmaf(q4.x, ka[c].x, s1); s1 = fmaf(q4.y, ka[c].y, s1);
                s1 = fmaf(q4.z, ka[c].z, s1); s1 = fmaf(q4.w, ka[c].w, s1);
                s2 = fmaf(q4.x, kb[c].x, s2); s2 = fmaf(q4.y, kb[c].y, s2);
                s2 = fmaf(q4.z, kb[c].z, s2); s2 = fmaf(q4.w, kb[c].w, s2);
            }
            S[qr][ja] = s1;
            S[qr][jb] = s2;
        }
    }
    __syncthreads();

    // Phase B: softmax over each row (4 waves x 2 rows)
    {
        int w = tid >> 6, lane = tid & 63;
        for (int r = w * 2; r < w * 2 + 2; ++r) {
            float vals[16];
            float m = -1e30f;
            #pragma unroll
            for (int i = 0; i < 16; ++i) {
                vals[i] = S[r][lane + i * 64];
                m = fmaxf(m, vals[i]);
            }
            #pragma unroll
            for (int off = 32; off; off >>= 1) m = fmaxf(m, __shfl_xor(m, off, 64));
            float sum = 0.0f;
            #pragma unroll
            for (int i = 0; i < 16; ++i) {
                float e = __expf(vals[i] - m);
                S[r][lane + i * 64] = e;
                sum += e;
            }
            #pragma unroll
            for (int off = 32; off; off >>= 1) sum += __shfl_xor(sum, off, 64);
            if (lane == 0) sums[r] = sum;
        }
    }
    __syncthreads();

    // Phase C: O = P @ V. thread -> (qr, d-chunk, j-quarter)
    {
        int dc = tid & 7;         // float4 chunk of d (8 x 4 = 32)
        int qrr = tid >> 3;       // 0..31
        int qr = qrr & 7, jq = qrr >> 3;   // j-quarter: 256 each
        float4 acc = make_float4(0.f, 0.f, 0.f, 0.f);
        for (int jj = 0; jj < 64; ++jj) {
            int j = jq * 256 + jj * 4;
            float4 p4 = *(const float4*)&S[qr][j];
            const float* vr = vbase + (size_t)j * 768 + dc * 4;
            float4 v0 = *(const float4*)vr;
            float4 v1 = *(const float4*)(vr + 768);
            float4 v2 = *(const float4*)(vr + 1536);
            float4 v3 = *(const float4*)(vr + 2304);
            acc.x += p4.x * v0.x + p4.y * v1.x + p4.z * v2.x + p4.w * v3.x;
            acc.y += p4.x * v0.y + p4.y * v1.y + p4.z * v2.y + p4.w * v3.y;
            acc.z += p4.x * v0.z + p4.y * v1.z + p4.z * v2.z + p4.w * v3.z;
            acc.w += p4.x * v0.w + p4.y * v1.w + p4.z * v2.w + p4.w * v3.w;
        }
        *(float4*)&Opart[qrr][dc * 4] = acc;
    }
    __syncthreads();

    // combine j-quarters, normalize, write
    if (tid < TQ * 32) {
        int qr = tid >> 5, d = tid & 31;
        float val = (Opart[qr][d] + Opart[qr + 8][d] + Opart[qr + 16][d] + Opart[qr + 24][d])
                    / sums[qr];
        o[((size_t)(b * Ndim + n0 + qr)) * INdim + h * 32 + d] = val;
    }
}

// ---------------------------------------------------------------------------
// launch
// ---------------------------------------------------------------------------
extern "C" void kernel_launch(void* const* d_in, const int* in_sizes, int n_in,
                              void* d_out, int out_size, void* d_ws, size_t ws_size,
                              hipStream_t stream) {
    const float* x     = (const float*)d_in[0];
    // d_in[1] = coords: unused by the reference
    const float* g1    = (const float*)d_in[2];
    const float* b1    = (const float*)d_in[3];
    const float* Wqkv  = (const float*)d_in[4];
    const float* Wproj = (const float*)d_in[5];
    const float* bproj = (const float*)d_in[6];
    const float* g2    = (const float*)d_in[7];
    const float* b2    = (const float*)d_in[8];
    const float* W1    = (const float*)d_in[9];
    const float* bb1   = (const float*)d_in[10];
    const float* W2    = (const float*)d_in[11];
    const float* bb2   = (const float*)d_in[12];
    float* out = (float*)d_out;

    // workspace layout (needs 96 MiB):
    //   h    [0,16M)   qkv [16M,64M)   o [64M,80M)   xnew [80M,96M)
    //   h2 reuses h;   mid [16M,80M) reuses qkv+o
    char* ws = (char*)d_ws;
    float* h    = (float*)(ws);
    float* qkv  = (float*)(ws + (size_t)(16u << 20));
    float* oat  = (float*)(ws + (size_t)(64u << 20));
    float* xnew = (float*)(ws + (size_t)(80u << 20));
    float* h2   = h;
    float* mid  = (float*)(ws + (size_t)(16u << 20));

    // 1) LN1: x -> h
    ln_kernel<<<Tdim, 256, 0, stream>>>(x, g1, b1, h);
    // 2) qkv = h @ Wqkv^T   [16384 x 768]
    gemm_kernel<EPI_NONE><<<dim3(768 / 64, Tdim / 128), 256, 0, stream>>>(
        h, Wqkv, qkv, Tdim, 768, 256, nullptr, nullptr, nullptr);
    // 3) attention -> oat [16384 x 256]
    attn_kernel<<<dim3(Ndim / TQ, Bdim * Hdim), 256, 0, stream>>>(qkv, oat);
    // 4) xnew = oat @ Wproj^T + bproj + h + x
    gemm_kernel<EPI_PROJ><<<dim3(256 / 64, Tdim / 128), 256, 0, stream>>>(
        oat, Wproj, xnew, Tdim, 256, 256, bproj, h, x);
    // 5) LN2: xnew -> h2
    ln_kernel<<<Tdim, 256, 0, stream>>>(xnew, g2, b2, h2);
    // 6) mid = gelu(h2 @ W1^T + bb1)   [16384 x 1024]
    gemm_kernel<EPI_GELU><<<dim3(1024 / 64, Tdim / 128), 256, 0, stream>>>(
        h2, W1, mid, Tdim, 1024, 256, bb1, nullptr, nullptr);
    // 7) out = xnew + mid @ W2^T + bb2
    gemm_kernel<EPI_RES><<<dim3(256 / 64, Tdim / 128), 256, 0, stream>>>(
        mid, W2, out, Tdim, 256, 1024, bb2, xnew, nullptr);
}

// Round 2
// 561.255 us; speedup vs baseline: 3.3632x; 3.3632x over previous
//
#include <hip/hip_runtime.h>
#include <hip/hip_bf16.h>
#include <math.h>

// Shapes (fixed by the reference)
#define Bdim 16
#define Ndim 1024
#define Ddim 256
#define Hdim 8
#define HDdim 32
#define INdim 256
#define HIDdim 1024
#define Tdim (Bdim * Ndim)   // 16384 rows

typedef __attribute__((ext_vector_type(8)))  short bf16x8;
typedef __attribute__((ext_vector_type(4)))  short bf16x4;
typedef __attribute__((ext_vector_type(16))) float f32x16;

__device__ inline short f2bf(float x) {
    union { __hip_bfloat16 b; short s; } u;
    u.b = __float2bfloat16(x);
    return u.s;
}

__device__ inline bf16x8 cvt8(float4 a, float4 b) {
    bf16x8 r;
    r[0] = f2bf(a.x); r[1] = f2bf(a.y); r[2] = f2bf(a.z); r[3] = f2bf(a.w);
    r[4] = f2bf(b.x); r[5] = f2bf(b.y); r[6] = f2bf(b.z); r[7] = f2bf(b.w);
    return r;
}

// ---------------------------------------------------------------------------
// LayerNorm: one block per row (D=256, 256 threads)
// ---------------------------------------------------------------------------
__global__ __launch_bounds__(256) void ln_kernel(const float* __restrict__ x,
                                                 const float* __restrict__ g,
                                                 const float* __restrict__ b,
                                                 float* __restrict__ out) {
    int row = blockIdx.x;
    int tid = threadIdx.x;
    float v = x[(size_t)row * Ddim + tid];
    float s = v, s2 = v * v;
    #pragma unroll
    for (int off = 32; off; off >>= 1) {
        s  += __shfl_xor(s,  off, 64);
        s2 += __shfl_xor(s2, off, 64);
    }
    __shared__ float ws[8];
    int w = tid >> 6;
    if ((tid & 63) == 0) { ws[w] = s; ws[w + 4] = s2; }
    __syncthreads();
    s  = ws[0] + ws[1] + ws[2] + ws[3];
    s2 = ws[4] + ws[5] + ws[6] + ws[7];
    float mu   = s * (1.0f / Ddim);
    float var  = s2 * (1.0f / Ddim) - mu * mu;
    float rstd = rsqrtf(var + 1e-5f);
    out[(size_t)row * Ddim + tid] = (v - mu) * rstd * g[tid] + b[tid];
}

// ---------------------------------------------------------------------------
// fp32 tiled GEMM: C[M,N] = A[M,K] @ W[N,K]^T (+ epilogue)  (unchanged)
// ---------------------------------------------------------------------------
#define EPI_NONE 0
#define EPI_PROJ 1
#define EPI_GELU 2
#define EPI_RES  3

__device__ inline float gelu_exact(float v) {
    return 0.5f * v * (1.0f + erff(v * 0.70710678118654752f));
}

template <int EPI>
__global__ __launch_bounds__(256) void gemm_kernel(const float* __restrict__ A,
                                                   const float* __restrict__ W,
                                                   float* __restrict__ C,
                                                   int M, int N, int K,
                                                   const float* __restrict__ bias,
                                                   const float* __restrict__ add1,
                                                   const float* __restrict__ add2) {
    __shared__ float As[16][132];
    __shared__ float Wsh[16][68];
    int tid = threadIdx.x;
    int bn = blockIdx.x, bm = blockIdx.y;
    int m0 = bm * 128, n0 = bn * 64;
    int tx = tid & 15, ty = tid >> 4;

    float acc[8][4];
    #pragma unroll
    for (int i = 0; i < 8; ++i)
        #pragma unroll
        for (int j = 0; j < 4; ++j) acc[i][j] = 0.0f;

    for (int k0 = 0; k0 < K; k0 += 16) {
        #pragma unroll
        for (int i = 0; i < 2; ++i) {
            int f4 = tid + i * 256;
            int r = f4 >> 2, c = f4 & 3;
            float4 v = *(const float4*)&A[(size_t)(m0 + r) * K + k0 + c * 4];
            As[c * 4 + 0][r] = v.x;
            As[c * 4 + 1][r] = v.y;
            As[c * 4 + 2][r] = v.z;
            As[c * 4 + 3][r] = v.w;
        }
        {
            int r = tid >> 2, c = tid & 3;
            float4 v = *(const float4*)&W[(size_t)(n0 + r) * K + k0 + c * 4];
            Wsh[c * 4 + 0][r] = v.x;
            Wsh[c * 4 + 1][r] = v.y;
            Wsh[c * 4 + 2][r] = v.z;
            Wsh[c * 4 + 3][r] = v.w;
        }
        __syncthreads();
        #pragma unroll
        for (int kk = 0; kk < 16; ++kk) {
            float4 a0 = *(const float4*)&As[kk][ty * 8];
            float4 a1 = *(const float4*)&As[kk][ty * 8 + 4];
            float4 w0 = *(const float4*)&Wsh[kk][tx * 4];
            float av[8] = {a0.x, a0.y, a0.z, a0.w, a1.x, a1.y, a1.z, a1.w};
            float wv[4] = {w0.x, w0.y, w0.z, w0.w};
            #pragma unroll
            for (int i = 0; i < 8; ++i)
                #pragma unroll
                for (int j = 0; j < 4; ++j)
                    acc[i][j] = fmaf(av[i], wv[j], acc[i][j]);
        }
        __syncthreads();
    }

    #pragma unroll
    for (int i = 0; i < 8; ++i) {
        int m = m0 + ty * 8 + i;
        size_t off = (size_t)m * N + n0 + tx * 4;
        float4 r = make_float4(acc[i][0], acc[i][1], acc[i][2], acc[i][3]);
        if (EPI != EPI_NONE) {
            float4 bi = *(const float4*)&bias[n0 + tx * 4];
            r.x += bi.x; r.y += bi.y; r.z += bi.z; r.w += bi.w;
        }
        if (EPI == EPI_GELU) {
            r.x = gelu_exact(r.x); r.y = gelu_exact(r.y);
            r.z = gelu_exact(r.z); r.w = gelu_exact(r.w);
        }
        if (EPI == EPI_PROJ) {
            float4 h4 = *(const float4*)&add1[off];
            float4 x4 = *(const float4*)&add2[off];
            r.x += h4.x + x4.x; r.y += h4.y + x4.y;
            r.z += h4.z + x4.z; r.w += h4.w + x4.w;
        }
        if (EPI == EPI_RES) {
            float4 a4 = *(const float4*)&add1[off];
            r.x += a4.x; r.y += a4.y; r.z += a4.z; r.w += a4.w;
        }
        *(float4*)&C[off] = r;
    }
}

// ---------------------------------------------------------------------------
// MFMA attention (bf16, 32x32x16). One block = one (b,head) x 128 queries.
// 4 waves x 32 queries; K/V staged fp32->bf16 in 128-row LDS chunks.
// S^T = K·Q^T so softmax is per-lane (col = query); P transits via per-wave
// LDS tile into the PV A-operand.  Maxless softmax (scores bounded ~O(1)).
// ---------------------------------------------------------------------------
#define KVPAD 40   // bf16 elems per LDS row (32 data + 8 pad); keeps 16B align
#define CHUNK 128

__global__ __launch_bounds__(256) void attn_mfma_kernel(const float* __restrict__ qkv,
                                                        float* __restrict__ o) {
    __shared__ short Ks[CHUNK * KVPAD];
    __shared__ short Vs[CHUNK * KVPAD];
    __shared__ short Ps[4][32 * KVPAD];   // per-wave P tile: 32q x 32j (pad)

    const int tid = threadIdx.x;
    const int w = tid >> 6;          // wave 0..3
    const int lane = tid & 63;
    const int col = lane & 31;       // q (in S^T) / d (in O) / j-row (K A-frag)
    const int half_id = lane >> 5;   // k-half selector in MFMA frags

    const int bh = blockIdx.y;
    const int b = bh >> 3, head = bh & 7;
    const int q0w = blockIdx.x * 128 + w * 32;      // this wave's first query
    const float scale = 0.17677669529663689f;       // 32^-0.5

    const size_t qkvb = (size_t)b * Ndim * 768;

    // ---- Q fragments (B-operand of S^T = K·Q^T), loaded once ----
    // B[k=hd][n=q]: lane col=q holds Q[q][kh*16 + half_id*8 + jj] * scale
    bf16x8 qf[2];
    {
        const float* qrow = qkv + qkvb + (size_t)(q0w + col) * 768 + head * 32;
        #pragma unroll
        for (int kh = 0; kh < 2; ++kh) {
            int d0 = kh * 16 + half_id * 8;
            float4 f0 = *(const float4*)(qrow + d0);
            float4 f1 = *(const float4*)(qrow + d0 + 4);
            f0.x *= scale; f0.y *= scale; f0.z *= scale; f0.w *= scale;
            f1.x *= scale; f1.y *= scale; f1.z *= scale; f1.w *= scale;
            qf[kh] = cvt8(f0, f1);
        }
    }

    f32x16 o_acc = 0.0f;
    float l_part = 0.0f;

    for (int c = 0; c < Ndim / CHUNK; ++c) {
        if (c) __syncthreads();
        // ---- stage K,V chunk (rows c*128..+127, 32 dims, fp32 -> bf16) ----
        {
            int r = tid >> 1, hv = tid & 1;   // row, 16-elem half
            const float* src = qkv + qkvb + (size_t)(c * CHUNK + r) * 768
                               + head * 32 + hv * 16;
            float4 k0 = *(const float4*)(src + 256);
            float4 k1 = *(const float4*)(src + 260);
            float4 k2 = *(const float4*)(src + 264);
            float4 k3 = *(const float4*)(src + 268);
            float4 v0 = *(const float4*)(src + 512);
            float4 v1 = *(const float4*)(src + 516);
            float4 v2 = *(const float4*)(src + 520);
            float4 v3 = *(const float4*)(src + 524);
            *(bf16x8*)&Ks[r * KVPAD + hv * 16]     = cvt8(k0, k1);
            *(bf16x8*)&Ks[r * KVPAD + hv * 16 + 8] = cvt8(k2, k3);
            *(bf16x8*)&Vs[r * KVPAD + hv * 16]     = cvt8(v0, v1);
            *(bf16x8*)&Vs[r * KVPAD + hv * 16 + 8] = cvt8(v2, v3);
        }
        __syncthreads();

        // ---- 4 j-tiles of 32 per chunk ----
        #pragma unroll
        for (int jt = 0; jt < 4; ++jt) {
            // S^T tile = K·Q^T : A = K rows (lane col = j-local)
            bf16x8 kf0 = *(bf16x8*)&Ks[(jt * 32 + col) * KVPAD + half_id * 8];
            bf16x8 kf1 = *(bf16x8*)&Ks[(jt * 32 + col) * KVPAD + 16 + half_id * 8];
            f32x16 s_acc = 0.0f;
            s_acc = __builtin_amdgcn_mfma_f32_32x32x16_bf16(kf0, qf[0], s_acc, 0, 0, 0);
            s_acc = __builtin_amdgcn_mfma_f32_32x32x16_bf16(kf1, qf[1], s_acc, 0, 0, 0);

            // exp (maxless), accumulate l, pack P into per-wave LDS tile.
            // C-layout: value at (j16 = (r&3)+8*(r>>2)+4*half_id, q = col).
            #pragma unroll
            for (int g = 0; g < 4; ++g) {
                float e0 = __expf(s_acc[g * 4 + 0]);
                float e1 = __expf(s_acc[g * 4 + 1]);
                float e2 = __expf(s_acc[g * 4 + 2]);
                float e3 = __expf(s_acc[g * 4 + 3]);
                l_part += (e0 + e1) + (e2 + e3);
                bf16x4 p4;
                p4[0] = f2bf(e0); p4[1] = f2bf(e1); p4[2] = f2bf(e2); p4[3] = f2bf(e3);
                *(bf16x4*)&Ps[w][col * KVPAD + g * 8 + half_id * 4] = p4;
            }

            // PV: O += P·V (two k=16 windows covering this tile's 32 j)
            #pragma unroll
            for (int kw = 0; kw < 2; ++kw) {
                bf16x8 pf = *(bf16x8*)&Ps[w][col * KVPAD + kw * 16 + half_id * 8];
                bf16x8 vf;
                #pragma unroll
                for (int jj = 0; jj < 8; ++jj)
                    vf[jj] = Vs[(jt * 32 + kw * 16 + half_id * 8 + jj) * KVPAD + col];
                o_acc = __builtin_amdgcn_mfma_f32_32x32x16_bf16(pf, vf, o_acc, 0, 0, 0);
            }
        }
    }

    // ---- epilogue: normalize by l, write O (fp32) ----
    float l_tot = l_part + __shfl_xor(l_part, 32, 64);
    #pragma unroll
    for (int r = 0; r < 16; ++r) {
        int q_r = (r & 3) + 8 * (r >> 2) + 4 * half_id;   // row index in O tile
        float lr = __shfl(l_tot, q_r, 64);
        size_t gq = (size_t)(b * Ndim + q0w + q_r);
        o[gq * INdim + head * 32 + col] = o_acc[r] / lr;
    }
}

// ---------------------------------------------------------------------------
// launch
// ---------------------------------------------------------------------------
extern "C" void kernel_launch(void* const* d_in, const int* in_sizes, int n_in,
                              void* d_out, int out_size, void* d_ws, size_t ws_size,
                              hipStream_t stream) {
    const float* x     = (const float*)d_in[0];
    const float* g1    = (const float*)d_in[2];
    const float* b1    = (const float*)d_in[3];
    const float* Wqkv  = (const float*)d_in[4];
    const float* Wproj = (const float*)d_in[5];
    const float* bproj = (const float*)d_in[6];
    const float* g2    = (const float*)d_in[7];
    const float* b2    = (const float*)d_in[8];
    const float* W1    = (const float*)d_in[9];
    const float* bb1   = (const float*)d_in[10];
    const float* W2    = (const float*)d_in[11];
    const float* bb2   = (const float*)d_in[12];
    float* out = (float*)d_out;

    char* ws = (char*)d_ws;
    float* h    = (float*)(ws);
    float* qkv  = (float*)(ws + (size_t)(16u << 20));
    float* oat  = (float*)(ws + (size_t)(64u << 20));
    float* xnew = (float*)(ws + (size_t)(80u << 20));
    float* h2   = h;
    float* mid  = (float*)(ws + (size_t)(16u << 20));

    // 1) LN1: x -> h
    ln_kernel<<<Tdim, 256, 0, stream>>>(x, g1, b1, h);
    // 2) qkv = h @ Wqkv^T   [16384 x 768]
    gemm_kernel<EPI_NONE><<<dim3(768 / 64, Tdim / 128), 256, 0, stream>>>(
        h, Wqkv, qkv, Tdim, 768, 256, nullptr, nullptr, nullptr);
    // 3) attention -> oat [16384 x 256]
    attn_mfma_kernel<<<dim3(Ndim / 128, Bdim * Hdim), 256, 0, stream>>>(qkv, oat);
    // 4) xnew = oat @ Wproj^T + bproj + h + x
    gemm_kernel<EPI_PROJ><<<dim3(256 / 64, Tdim / 128), 256, 0, stream>>>(
        oat, Wproj, xnew, Tdim, 256, 256, bproj, h, x);
    // 5) LN2: xnew -> h2
    ln_kernel<<<Tdim, 256, 0, stream>>>(xnew, g2, b2, h2);
    // 6) mid = gelu(h2 @ W1^T + bb1)   [16384 x 1024]
    gemm_kernel<EPI_GELU><<<dim3(1024 / 64, Tdim / 128), 256, 0, stream>>>(
        h2, W1, mid, Tdim, 1024, 256, bb1, nullptr, nullptr);
    // 7) out = xnew + mid @ W2^T + bb2
    gemm_kernel<EPI_RES><<<dim3(256 / 64, Tdim / 128), 256, 0, stream>>>(
        mid, W2, out, Tdim, 256, 1024, bb2, xnew, nullptr);
}

// Round 5
// 300.752 us; speedup vs baseline: 6.2762x; 1.8662x over previous
//
#include <hip/hip_runtime.h>
#include <hip/hip_bf16.h>
#include <math.h>

// Shapes (fixed by the reference)
#define Bdim 16
#define Ndim 1024
#define Ddim 256
#define Hdim 8
#define HDdim 32
#define INdim 256
#define HIDdim 1024
#define Tdim (Bdim * Ndim)   // 16384 rows

typedef __attribute__((ext_vector_type(8)))  short bf16x8;
typedef __attribute__((ext_vector_type(4)))  short bf16x4;
typedef __attribute__((ext_vector_type(16))) float f32x16;

__device__ inline short f2bf(float x) {
    union { __hip_bfloat16 b; short s; } u;
    u.b = __float2bfloat16(x);
    return u.s;
}

__device__ inline bf16x8 cvt8(float4 a, float4 b) {
    bf16x8 r;
    r[0] = f2bf(a.x); r[1] = f2bf(a.y); r[2] = f2bf(a.z); r[3] = f2bf(a.w);
    r[4] = f2bf(b.x); r[5] = f2bf(b.y); r[6] = f2bf(b.z); r[7] = f2bf(b.w);
    return r;
}

__device__ inline float gelu_exact(float v) {
    return 0.5f * v * (1.0f + erff(v * 0.70710678118654752f));
}

// ---------------------------------------------------------------------------
// LayerNorm: one block per row (D=256, 256 threads)  [R2-proven]
// ---------------------------------------------------------------------------
__global__ __launch_bounds__(256) void ln_kernel(const float* __restrict__ x,
                                                 const float* __restrict__ g,
                                                 const float* __restrict__ b,
                                                 float* __restrict__ out) {
    int row = blockIdx.x;
    int tid = threadIdx.x;
    float v = x[(size_t)row * Ddim + tid];
    float s = v, s2 = v * v;
    #pragma unroll
    for (int off = 32; off; off >>= 1) {
        s  += __shfl_xor(s,  off, 64);
        s2 += __shfl_xor(s2, off, 64);
    }
    __shared__ float ws[8];
    int w = tid >> 6;
    if ((tid & 63) == 0) { ws[w] = s; ws[w + 4] = s2; }
    __syncthreads();
    s  = ws[0] + ws[1] + ws[2] + ws[3];
    s2 = ws[4] + ws[5] + ws[6] + ws[7];
    float mu   = s * (1.0f / Ddim);
    float var  = s2 * (1.0f / Ddim) - mu * mu;
    float rstd = rsqrtf(var + 1e-5f);
    out[(size_t)row * Ddim + tid] = (v - mu) * rstd * g[tid] + b[tid];
}

// ---------------------------------------------------------------------------
// MFMA GEMM (fp32 in/out, bf16 compute): C[M,N] = A[M,K] @ W[N,K]^T (+ epi)
// Built ONLY from R2-proven pieces: mfma_f32_32x32x16_bf16 with the exact
// fragment addressing of the R2 attention kernel (kf0/kf1 pattern), fp32->bf16
// cvt8 staging, padded-row LDS. 128x128 tile, BK=32, 4 waves x 2x2 of 32x32.
// ---------------------------------------------------------------------------
#define EPI_NONE 0
#define EPI_PROJ 1   // acc + bias[n] + add1[off] + add2[off]
#define EPI_GELU 2   // gelu(acc + bias[n])
#define EPI_RES  3   // acc + bias[n] + add1[off]

#define GPAD 40      // shorts per LDS row (32 data + 8 pad)

template <int EPI>
__global__ __launch_bounds__(256) void gemm_mfma(const float* __restrict__ A,
                                                 const float* __restrict__ W,
                                                 float* __restrict__ C,
                                                 int M, int N, int K,
                                                 const float* __restrict__ bias,
                                                 const float* __restrict__ add1,
                                                 const float* __restrict__ add2) {
    __shared__ short As[128 * GPAD];   // 10 KB
    __shared__ short Bs[128 * GPAD];   // 10 KB
    const int tid = threadIdx.x, w = tid >> 6, lane = tid & 63;
    const int col = lane & 31;        // row-within-32-tile selector (R2 naming)
    const int half_id = lane >> 5;    // k-half selector (R2 naming)
    const int m0 = blockIdx.y * 128, n0 = blockIdx.x * 128;
    const int wm = (w & 1) * 64, wn = (w >> 1) * 64;

    f32x16 acc[2][2];
    acc[0][0] = 0.0f; acc[0][1] = 0.0f; acc[1][0] = 0.0f; acc[1][1] = 0.0f;

    const int sr = tid >> 1;     // staging row (0..127)
    const int sh = tid & 1;      // staging k-half (16 floats)

    for (int k0 = 0; k0 < K; k0 += 32) {
        if (k0) __syncthreads();
        {
            const float* srcA = &A[(size_t)(m0 + sr) * K + k0 + sh * 16];
            const float* srcW = &W[(size_t)(n0 + sr) * K + k0 + sh * 16];
            float4 a0 = *(const float4*)&srcA[0];
            float4 a1 = *(const float4*)&srcA[4];
            float4 a2 = *(const float4*)&srcA[8];
            float4 a3 = *(const float4*)&srcA[12];
            float4 w0 = *(const float4*)&srcW[0];
            float4 w1 = *(const float4*)&srcW[4];
            float4 w2 = *(const float4*)&srcW[8];
            float4 w3 = *(const float4*)&srcW[12];
            *(bf16x8*)&As[sr * GPAD + sh * 16]     = cvt8(a0, a1);
            *(bf16x8*)&As[sr * GPAD + sh * 16 + 8] = cvt8(a2, a3);
            *(bf16x8*)&Bs[sr * GPAD + sh * 16]     = cvt8(w0, w1);
            *(bf16x8*)&Bs[sr * GPAD + sh * 16 + 8] = cvt8(w2, w3);
        }
        __syncthreads();

        // fragment reads: exact R2 kf0/kf1 addressing
        #pragma unroll
        for (int ks = 0; ks < 2; ++ks) {          // k-step of 16 within BK=32
            bf16x8 af[2], bfv[2];
            #pragma unroll
            for (int t = 0; t < 2; ++t) {
                af[t]  = *(const bf16x8*)&As[(wm + t * 32 + col) * GPAD + ks * 16 + half_id * 8];
                bfv[t] = *(const bf16x8*)&Bs[(wn + t * 32 + col) * GPAD + ks * 16 + half_id * 8];
            }
            #pragma unroll
            for (int tm = 0; tm < 2; ++tm)
                #pragma unroll
                for (int tn = 0; tn < 2; ++tn)
                    acc[tm][tn] = __builtin_amdgcn_mfma_f32_32x32x16_bf16(
                        af[tm], bfv[tn], acc[tm][tn], 0, 0, 0);
        }
    }

    // epilogue: C/D layout col=lane&31, row=(reg&3)+8*(reg>>2)+4*(lane>>5)
    // (exact R2 q_r formula)
    #pragma unroll
    for (int tm = 0; tm < 2; ++tm) {
        #pragma unroll
        for (int r = 0; r < 16; ++r) {
            int row = m0 + wm + tm * 32 + (r & 3) + 8 * (r >> 2) + 4 * half_id;
            #pragma unroll
            for (int tn = 0; tn < 2; ++tn) {
                int cn = n0 + wn + tn * 32 + col;
                size_t off = (size_t)row * N + cn;
                float v = acc[tm][tn][r];
                if (EPI != EPI_NONE) v += bias[cn];
                if (EPI == EPI_GELU) v = gelu_exact(v);
                if (EPI == EPI_PROJ) v += add1[off] + add2[off];
                if (EPI == EPI_RES)  v += add1[off];
                C[off] = v;
            }
        }
    }
}

// ---------------------------------------------------------------------------
// MFMA attention (fp32 in/out) — byte-identical to R2-passing version.
// ---------------------------------------------------------------------------
#define KVPAD 40
#define CHUNK 128

__global__ __launch_bounds__(256) void attn_mfma_kernel(const float* __restrict__ qkv,
                                                        float* __restrict__ o) {
    __shared__ short Ks[CHUNK * KVPAD];
    __shared__ short Vs[CHUNK * KVPAD];
    __shared__ short Ps[4][32 * KVPAD];

    const int tid = threadIdx.x;
    const int w = tid >> 6;
    const int lane = tid & 63;
    const int col = lane & 31;
    const int half_id = lane >> 5;

    const int bh = blockIdx.y;
    const int b = bh >> 3, head = bh & 7;
    const int q0w = blockIdx.x * 128 + w * 32;
    const float scale = 0.17677669529663689f;  // 32^-0.5

    const size_t qkvb = (size_t)b * Ndim * 768;

    bf16x8 qf[2];
    {
        const float* qrow = qkv + qkvb + (size_t)(q0w + col) * 768 + head * 32;
        #pragma unroll
        for (int kh = 0; kh < 2; ++kh) {
            int d0 = kh * 16 + half_id * 8;
            float4 f0 = *(const float4*)(qrow + d0);
            float4 f1 = *(const float4*)(qrow + d0 + 4);
            f0.x *= scale; f0.y *= scale; f0.z *= scale; f0.w *= scale;
            f1.x *= scale; f1.y *= scale; f1.z *= scale; f1.w *= scale;
            qf[kh] = cvt8(f0, f1);
        }
    }

    f32x16 o_acc = 0.0f;
    float l_part = 0.0f;

    for (int c = 0; c < Ndim / CHUNK; ++c) {
        if (c) __syncthreads();
        {
            int r = tid >> 1, hv = tid & 1;
            const float* src = qkv + qkvb + (size_t)(c * CHUNK + r) * 768
                               + head * 32 + hv * 16;
            float4 k0 = *(const float4*)(src + 256);
            float4 k1 = *(const float4*)(src + 260);
            float4 k2 = *(const float4*)(src + 264);
            float4 k3 = *(const float4*)(src + 268);
            float4 v0 = *(const float4*)(src + 512);
            float4 v1 = *(const float4*)(src + 516);
            float4 v2 = *(const float4*)(src + 520);
            float4 v3 = *(const float4*)(src + 524);
            *(bf16x8*)&Ks[r * KVPAD + hv * 16]     = cvt8(k0, k1);
            *(bf16x8*)&Ks[r * KVPAD + hv * 16 + 8] = cvt8(k2, k3);
            *(bf16x8*)&Vs[r * KVPAD + hv * 16]     = cvt8(v0, v1);
            *(bf16x8*)&Vs[r * KVPAD + hv * 16 + 8] = cvt8(v2, v3);
        }
        __syncthreads();

        #pragma unroll
        for (int jt = 0; jt < 4; ++jt) {
            bf16x8 kf0 = *(bf16x8*)&Ks[(jt * 32 + col) * KVPAD + half_id * 8];
            bf16x8 kf1 = *(bf16x8*)&Ks[(jt * 32 + col) * KVPAD + 16 + half_id * 8];
            f32x16 s_acc = 0.0f;
            s_acc = __builtin_amdgcn_mfma_f32_32x32x16_bf16(kf0, qf[0], s_acc, 0, 0, 0);
            s_acc = __builtin_amdgcn_mfma_f32_32x32x16_bf16(kf1, qf[1], s_acc, 0, 0, 0);

            #pragma unroll
            for (int g = 0; g < 4; ++g) {
                float e0 = __expf(s_acc[g * 4 + 0]);
                float e1 = __expf(s_acc[g * 4 + 1]);
                float e2 = __expf(s_acc[g * 4 + 2]);
                float e3 = __expf(s_acc[g * 4 + 3]);
                l_part += (e0 + e1) + (e2 + e3);
                bf16x4 p4;
                p4[0] = f2bf(e0); p4[1] = f2bf(e1); p4[2] = f2bf(e2); p4[3] = f2bf(e3);
                *(bf16x4*)&Ps[w][col * KVPAD + g * 8 + half_id * 4] = p4;
            }

            #pragma unroll
            for (int kw = 0; kw < 2; ++kw) {
                bf16x8 pf = *(bf16x8*)&Ps[w][col * KVPAD + kw * 16 + half_id * 8];
                bf16x8 vf;
                #pragma unroll
                for (int jj = 0; jj < 8; ++jj)
                    vf[jj] = Vs[(jt * 32 + kw * 16 + half_id * 8 + jj) * KVPAD + col];
                o_acc = __builtin_amdgcn_mfma_f32_32x32x16_bf16(pf, vf, o_acc, 0, 0, 0);
            }
        }
    }

    float l_tot = l_part + __shfl_xor(l_part, 32, 64);
    #pragma unroll
    for (int r = 0; r < 16; ++r) {
        int q_r = (r & 3) + 8 * (r >> 2) + 4 * half_id;
        float lr = __shfl(l_tot, q_r, 64);
        size_t gq = (size_t)(b * Ndim + q0w + q_r);
        o[gq * INdim + head * 32 + col] = o_acc[r] / lr;
    }
}

// ---------------------------------------------------------------------------
// launch — R2 dataflow (all fp32 buffers), MFMA GEMMs
// ---------------------------------------------------------------------------
extern "C" void kernel_launch(void* const* d_in, const int* in_sizes, int n_in,
                              void* d_out, int out_size, void* d_ws, size_t ws_size,
                              hipStream_t stream) {
    const float* x     = (const float*)d_in[0];
    const float* g1    = (const float*)d_in[2];
    const float* b1    = (const float*)d_in[3];
    const float* Wqkv  = (const float*)d_in[4];
    const float* Wproj = (const float*)d_in[5];
    const float* bproj = (const float*)d_in[6];
    const float* g2    = (const float*)d_in[7];
    const float* b2    = (const float*)d_in[8];
    const float* W1    = (const float*)d_in[9];
    const float* bb1   = (const float*)d_in[10];
    const float* W2    = (const float*)d_in[11];
    const float* bb2   = (const float*)d_in[12];
    float* out = (float*)d_out;

    // R2 workspace layout (96 MiB):
    //   h [0,16M) | qkv [16M,64M) | oat [64M,80M) | xnew [80M,96M)
    //   h2 reuses h; mid [16M,80M) reuses qkv+oat
    char* ws = (char*)d_ws;
    float* h    = (float*)(ws);
    float* qkv  = (float*)(ws + (size_t)(16u << 20));
    float* oat  = (float*)(ws + (size_t)(64u << 20));
    float* xnew = (float*)(ws + (size_t)(80u << 20));
    float* h2   = h;
    float* mid  = (float*)(ws + (size_t)(16u << 20));

    // 1) LN1: x -> h
    ln_kernel<<<Tdim, 256, 0, stream>>>(x, g1, b1, h);
    // 2) qkv = h @ Wqkv^T   [16384 x 768]
    gemm_mfma<EPI_NONE><<<dim3(768 / 128, Tdim / 128), 256, 0, stream>>>(
        h, Wqkv, qkv, Tdim, 768, 256, nullptr, nullptr, nullptr);
    // 3) attention -> oat [16384 x 256]
    attn_mfma_kernel<<<dim3(Ndim / 128, Bdim * Hdim), 256, 0, stream>>>(qkv, oat);
    // 4) xnew = oat @ Wproj^T + bproj + h + x
    gemm_mfma<EPI_PROJ><<<dim3(256 / 128, Tdim / 128), 256, 0, stream>>>(
        oat, Wproj, xnew, Tdim, 256, 256, bproj, h, x);
    // 5) LN2: xnew -> h2
    ln_kernel<<<Tdim, 256, 0, stream>>>(xnew, g2, b2, h2);
    // 6) mid = gelu(h2 @ W1^T + bb1)   [16384 x 1024]
    gemm_mfma<EPI_GELU><<<dim3(1024 / 128, Tdim / 128), 256, 0, stream>>>(
        h2, W1, mid, Tdim, 1024, 256, bb1, nullptr, nullptr);
    // 7) out = xnew + mid @ W2^T + bb2
    gemm_mfma<EPI_RES><<<dim3(256 / 128, Tdim / 128), 256, 0, stream>>>(
        mid, W2, out, Tdim, 256, 1024, bb2, xnew, nullptr);
}

// Round 6
// 273.031 us; speedup vs baseline: 6.9135x; 1.1015x over previous
//
#include <hip/hip_runtime.h>
#include <hip/hip_bf16.h>
#include <math.h>

// Shapes (fixed by the reference)
#define Bdim 16
#define Ndim 1024
#define Ddim 256
#define Hdim 8
#define HDdim 32
#define INdim 256
#define HIDdim 1024
#define Tdim (Bdim * Ndim)   // 16384 rows

typedef __attribute__((ext_vector_type(8)))  short bf16x8;
typedef __attribute__((ext_vector_type(4)))  short bf16x4;
typedef __attribute__((ext_vector_type(16))) float f32x16;

__device__ inline short f2bf(float x) {
    union { __hip_bfloat16 b; short s; } u;
    u.b = __float2bfloat16(x);
    return u.s;
}

__device__ inline bf16x8 cvt8(float4 a, float4 b) {
    bf16x8 r;
    r[0] = f2bf(a.x); r[1] = f2bf(a.y); r[2] = f2bf(a.z); r[3] = f2bf(a.w);
    r[4] = f2bf(b.x); r[5] = f2bf(b.y); r[6] = f2bf(b.z); r[7] = f2bf(b.w);
    return r;
}

__device__ inline float gelu_exact(float v) {
    return 0.5f * v * (1.0f + erff(v * 0.70710678118654752f));
}

// ---------------------------------------------------------------------------
// LayerNorm: one block per row. Always writes bf16; optional fp32 copy.
// ---------------------------------------------------------------------------
__global__ __launch_bounds__(256) void ln_kernel(const float* __restrict__ x,
                                                 const float* __restrict__ g,
                                                 const float* __restrict__ b,
                                                 float* __restrict__ outf,
                                                 short* __restrict__ outb) {
    int row = blockIdx.x;
    int tid = threadIdx.x;
    float v = x[(size_t)row * Ddim + tid];
    float s = v, s2 = v * v;
    #pragma unroll
    for (int off = 32; off; off >>= 1) {
        s  += __shfl_xor(s,  off, 64);
        s2 += __shfl_xor(s2, off, 64);
    }
    __shared__ float ws[8];
    int w = tid >> 6;
    if ((tid & 63) == 0) { ws[w] = s; ws[w + 4] = s2; }
    __syncthreads();
    s  = ws[0] + ws[1] + ws[2] + ws[3];
    s2 = ws[4] + ws[5] + ws[6] + ws[7];
    float mu   = s * (1.0f / Ddim);
    float var  = s2 * (1.0f / Ddim) - mu * mu;
    float rstd = rsqrtf(var + 1e-5f);
    float r = (v - mu) * rstd * g[tid] + b[tid];
    if (outf) outf[(size_t)row * Ddim + tid] = r;
    outb[(size_t)row * Ddim + tid] = f2bf(r);
}

// ---------------------------------------------------------------------------
// MFMA GEMM (bf16 A, fp32 W cvt-in-staging): C[M,N] = A[M,K] @ W[N,K]^T (+epi)
// Core identical to R5-passing kernel: 128x128, BK=32, 4 waves x 2x2 of
// mfma_f32_32x32x16_bf16, R2-verified fragment addressing.
// Output: bf16 for EPI_NONE/EPI_GELU, fp32 for EPI_PROJ/EPI_RES.
// ---------------------------------------------------------------------------
#define EPI_NONE 0
#define EPI_PROJ 1   // fp32: acc + bias[n] + add1[off] + add2[off]
#define EPI_GELU 2   // bf16: gelu(acc + bias[n])
#define EPI_RES  3   // fp32: acc + bias[n] + add1[off]

#define GPAD 40      // shorts per LDS row (32 data + 8 pad)

template <int EPI>
__global__ __launch_bounds__(256) void gemm_mfma(const short* __restrict__ A,
                                                 const float* __restrict__ W,
                                                 void* __restrict__ Cv,
                                                 int M, int N, int K,
                                                 const float* __restrict__ bias,
                                                 const float* __restrict__ add1,
                                                 const float* __restrict__ add2) {
    __shared__ short As[128 * GPAD];   // 10 KB
    __shared__ short Bs[128 * GPAD];   // 10 KB
    const int tid = threadIdx.x, w = tid >> 6, lane = tid & 63;
    const int col = lane & 31;
    const int half_id = lane >> 5;
    const int m0 = blockIdx.y * 128, n0 = blockIdx.x * 128;
    const int wm = (w & 1) * 64, wn = (w >> 1) * 64;

    f32x16 acc[2][2];
    acc[0][0] = 0.0f; acc[0][1] = 0.0f; acc[1][0] = 0.0f; acc[1][1] = 0.0f;

    const int sr = tid >> 1;     // staging row (0..127)
    const int sh = tid & 1;      // staging k-half (16 elems)

    for (int k0 = 0; k0 < K; k0 += 32) {
        if (k0) __syncthreads();
        {
            // A: bf16 passthrough — TWO bf16x8 per thread (16 elems, full half)
            const short* srcA = &A[(size_t)(m0 + sr) * K + k0 + sh * 16];
            *(bf16x8*)&As[sr * GPAD + sh * 16]     = *(const bf16x8*)&srcA[0];
            *(bf16x8*)&As[sr * GPAD + sh * 16 + 8] = *(const bf16x8*)&srcA[8];
            // W: fp32 -> bf16 cvt in staging (R5-proven path)
            const float* srcW = &W[(size_t)(n0 + sr) * K + k0 + sh * 16];
            float4 w0 = *(const float4*)&srcW[0];
            float4 w1 = *(const float4*)&srcW[4];
            float4 w2 = *(const float4*)&srcW[8];
            float4 w3 = *(const float4*)&srcW[12];
            *(bf16x8*)&Bs[sr * GPAD + sh * 16]     = cvt8(w0, w1);
            *(bf16x8*)&Bs[sr * GPAD + sh * 16 + 8] = cvt8(w2, w3);
        }
        __syncthreads();

        #pragma unroll
        for (int ks = 0; ks < 2; ++ks) {
            bf16x8 af[2], bfv[2];
            #pragma unroll
            for (int t = 0; t < 2; ++t) {
                af[t]  = *(const bf16x8*)&As[(wm + t * 32 + col) * GPAD + ks * 16 + half_id * 8];
                bfv[t] = *(const bf16x8*)&Bs[(wn + t * 32 + col) * GPAD + ks * 16 + half_id * 8];
            }
            #pragma unroll
            for (int tm = 0; tm < 2; ++tm)
                #pragma unroll
                for (int tn = 0; tn < 2; ++tn)
                    acc[tm][tn] = __builtin_amdgcn_mfma_f32_32x32x16_bf16(
                        af[tm], bfv[tn], acc[tm][tn], 0, 0, 0);
        }
    }

    // epilogue: C/D layout col=lane&31, row=(reg&3)+8*(reg>>2)+4*(lane>>5)
    float* Cf = (float*)Cv;
    short* Cb = (short*)Cv;
    #pragma unroll
    for (int tm = 0; tm < 2; ++tm) {
        #pragma unroll
        for (int r = 0; r < 16; ++r) {
            int row = m0 + wm + tm * 32 + (r & 3) + 8 * (r >> 2) + 4 * half_id;
            #pragma unroll
            for (int tn = 0; tn < 2; ++tn) {
                int cn = n0 + wn + tn * 32 + col;
                size_t off = (size_t)row * N + cn;
                float v = acc[tm][tn][r];
                if (EPI != EPI_NONE) v += bias[cn];
                if (EPI == EPI_GELU) v = gelu_exact(v);
                if (EPI == EPI_PROJ) v += add1[off] + add2[off];
                if (EPI == EPI_RES)  v += add1[off];
                if (EPI == EPI_NONE || EPI == EPI_GELU) Cb[off] = f2bf(v);
                else                                    Cf[off] = v;
            }
        }
    }
}

// ---------------------------------------------------------------------------
// MFMA attention, bf16 in/out. Structure = R2/R5-proven; staging now a bf16
// passthrough with the FULL 16-elem copy per thread (the R3/R4 bug was
// copying only 8). Scale folded into exp.
// ---------------------------------------------------------------------------
#define KVPAD 40
#define CHUNK 128

__global__ __launch_bounds__(256) void attn_mfma_kernel(const short* __restrict__ qkv,
                                                        short* __restrict__ o) {
    __shared__ short Ks[CHUNK * KVPAD];
    __shared__ short Vs[CHUNK * KVPAD];
    __shared__ short Ps[4][32 * KVPAD];

    const int tid = threadIdx.x;
    const int w = tid >> 6;
    const int lane = tid & 63;
    const int col = lane & 31;
    const int half_id = lane >> 5;

    const int bh = blockIdx.y;
    const int b = bh >> 3, head = bh & 7;
    const int q0w = blockIdx.x * 128 + w * 32;
    const float scale = 0.17677669529663689f;  // 32^-0.5

    const size_t qkvb = (size_t)b * Ndim * 768;

    // Q fragments (B-operand of S^T = K·Q^T); raw bf16, scale applied in exp
    bf16x8 qf[2];
    {
        const short* qrow = qkv + qkvb + (size_t)(q0w + col) * 768 + head * 32;
        #pragma unroll
        for (int kh = 0; kh < 2; ++kh)
            qf[kh] = *(const bf16x8*)&qrow[kh * 16 + half_id * 8];
    }

    f32x16 o_acc = 0.0f;
    float l_part = 0.0f;

    for (int c = 0; c < Ndim / CHUNK; ++c) {
        if (c) __syncthreads();
        {
            int r = tid >> 1, hv = tid & 1;
            const short* src = qkv + qkvb + (size_t)(c * CHUNK + r) * 768
                               + head * 32 + hv * 16;
            *(bf16x8*)&Ks[r * KVPAD + hv * 16]     = *(const bf16x8*)&src[256];
            *(bf16x8*)&Ks[r * KVPAD + hv * 16 + 8] = *(const bf16x8*)&src[256 + 8];
            *(bf16x8*)&Vs[r * KVPAD + hv * 16]     = *(const bf16x8*)&src[512];
            *(bf16x8*)&Vs[r * KVPAD + hv * 16 + 8] = *(const bf16x8*)&src[512 + 8];
        }
        __syncthreads();

        #pragma unroll
        for (int jt = 0; jt < 4; ++jt) {
            bf16x8 kf0 = *(bf16x8*)&Ks[(jt * 32 + col) * KVPAD + half_id * 8];
            bf16x8 kf1 = *(bf16x8*)&Ks[(jt * 32 + col) * KVPAD + 16 + half_id * 8];
            f32x16 s_acc = 0.0f;
            s_acc = __builtin_amdgcn_mfma_f32_32x32x16_bf16(kf0, qf[0], s_acc, 0, 0, 0);
            s_acc = __builtin_amdgcn_mfma_f32_32x32x16_bf16(kf1, qf[1], s_acc, 0, 0, 0);

            #pragma unroll
            for (int g = 0; g < 4; ++g) {
                float e0 = __expf(s_acc[g * 4 + 0] * scale);
                float e1 = __expf(s_acc[g * 4 + 1] * scale);
                float e2 = __expf(s_acc[g * 4 + 2] * scale);
                float e3 = __expf(s_acc[g * 4 + 3] * scale);
                l_part += (e0 + e1) + (e2 + e3);
                bf16x4 p4;
                p4[0] = f2bf(e0); p4[1] = f2bf(e1); p4[2] = f2bf(e2); p4[3] = f2bf(e3);
                *(bf16x4*)&Ps[w][col * KVPAD + g * 8 + half_id * 4] = p4;
            }

            #pragma unroll
            for (int kw = 0; kw < 2; ++kw) {
                bf16x8 pf = *(bf16x8*)&Ps[w][col * KVPAD + kw * 16 + half_id * 8];
                bf16x8 vf;
                #pragma unroll
                for (int jj = 0; jj < 8; ++jj)
                    vf[jj] = Vs[(jt * 32 + kw * 16 + half_id * 8 + jj) * KVPAD + col];
                o_acc = __builtin_amdgcn_mfma_f32_32x32x16_bf16(pf, vf, o_acc, 0, 0, 0);
            }
        }
    }

    float l_tot = l_part + __shfl_xor(l_part, 32, 64);
    #pragma unroll
    for (int r = 0; r < 16; ++r) {
        int q_r = (r & 3) + 8 * (r >> 2) + 4 * half_id;
        float lr = __shfl(l_tot, q_r, 64);
        size_t gq = (size_t)(b * Ndim + q0w + q_r);
        o[gq * INdim + head * 32 + col] = f2bf(o_acc[r] / lr);
    }
}

// ---------------------------------------------------------------------------
// launch
// ---------------------------------------------------------------------------
extern "C" void kernel_launch(void* const* d_in, const int* in_sizes, int n_in,
                              void* d_out, int out_size, void* d_ws, size_t ws_size,
                              hipStream_t stream) {
    const float* x     = (const float*)d_in[0];
    const float* g1    = (const float*)d_in[2];
    const float* b1    = (const float*)d_in[3];
    const float* Wqkv  = (const float*)d_in[4];
    const float* Wproj = (const float*)d_in[5];
    const float* bproj = (const float*)d_in[6];
    const float* g2    = (const float*)d_in[7];
    const float* b2    = (const float*)d_in[8];
    const float* W1    = (const float*)d_in[9];
    const float* bb1   = (const float*)d_in[10];
    const float* W2    = (const float*)d_in[11];
    const float* bb2   = (const float*)d_in[12];
    float* out = (float*)d_out;

    // workspace (72 MiB):
    //   h fp32 [0,16M) | h_bf [16M,24M) | qkv_bf [24M,48M) | oat_bf [48M,56M)
    //   xnew fp32 [56M,72M) | mid_bf [24M,56M) reuses qkv_bf+oat_bf (dead)
    char* ws = (char*)d_ws;
    float* h      = (float*)(ws);
    short* h_bf   = (short*)(ws + (size_t)(16u << 20));
    short* qkv_bf = (short*)(ws + (size_t)(24u << 20));
    short* oat_bf = (short*)(ws + (size_t)(48u << 20));
    float* xnew   = (float*)(ws + (size_t)(56u << 20));
    short* mid_bf = (short*)(ws + (size_t)(24u << 20));

    // 1) LN1: x -> h (fp32, for proj residual) + h_bf (GEMM A)
    ln_kernel<<<Tdim, 256, 0, stream>>>(x, g1, b1, h, h_bf);
    // 2) qkv_bf = h_bf @ Wqkv^T   [16384 x 768] bf16 out
    gemm_mfma<EPI_NONE><<<dim3(768 / 128, Tdim / 128), 256, 0, stream>>>(
        h_bf, Wqkv, qkv_bf, Tdim, 768, 256, nullptr, nullptr, nullptr);
    // 3) attention -> oat_bf [16384 x 256]
    attn_mfma_kernel<<<dim3(Ndim / 128, Bdim * Hdim), 256, 0, stream>>>(qkv_bf, oat_bf);
    // 4) xnew = oat @ Wproj^T + bproj + h + x  (fp32 out)
    gemm_mfma<EPI_PROJ><<<dim3(256 / 128, Tdim / 128), 256, 0, stream>>>(
        oat_bf, Wproj, xnew, Tdim, 256, 256, bproj, h, x);
    // 5) LN2: xnew -> h_bf (bf16 only)
    ln_kernel<<<Tdim, 256, 0, stream>>>(xnew, g2, b2, nullptr, h_bf);
    // 6) mid_bf = gelu(h2 @ W1^T + bb1)   [16384 x 1024] bf16 out
    gemm_mfma<EPI_GELU><<<dim3(1024 / 128, Tdim / 128), 256, 0, stream>>>(
        h_bf, W1, mid_bf, Tdim, 1024, 256, bb1, nullptr, nullptr);
    // 7) out = xnew + mid @ W2^T + bb2  (fp32 out)
    gemm_mfma<EPI_RES><<<dim3(256 / 128, Tdim / 128), 256, 0, stream>>>(
        mid_bf, W2, out, Tdim, 256, 1024, bb2, xnew, nullptr);
}